// Round 11
// baseline (186.619 us; speedup 1.0000x reference)
//
#include <hip/hip_runtime.h>
#include <hip/hip_bf16.h>

typedef __attribute__((ext_vector_type(8))) short short8;
typedef __attribute__((ext_vector_type(4))) float f32x4;

#define B_ROWS 8192
#define DIM 256
#define CS 8                  // column slices -> grid.y (1024 cols each)
#define NT 16                 // 64-col tiles per slice
#define NSLICE (CS * 2)       // negp slices (col-slice x wch-half)
#define MARGIN_F 0.2f
#define BUCKET_CAP 32

// counted vmcnt wait (T4): literal immediate, memory clobber pins ordering
#define WAITV(n) asm volatile("s_waitcnt vmcnt(" #n ")" ::: "memory")

__device__ __forceinline__ unsigned short f2bf(float x) {
  unsigned int u = __float_as_uint(x);
  unsigned int r = (u + 0x7fffu + ((u >> 16) & 1u)) >> 16;
  return (unsigned short)r;
}
__device__ __forceinline__ float bf2f(unsigned short h) {
  return __uint_as_float(((unsigned int)h) << 16);
}

__device__ __forceinline__ void gload_lds16(const void* g, void* l) {
  __builtin_amdgcn_global_load_lds(
      (const __attribute__((address_space(1))) unsigned int*)g,
      (__attribute__((address_space(3))) unsigned int*)l, 16, 0, 0);
}

// ---- 1. normalize rows -> bf16 e; build label->rows bucket index ----
__global__ __launch_bounds__(256) void k_norm_index(
    const float* __restrict__ emb, const int* __restrict__ labels,
    unsigned short* __restrict__ ebf, int* __restrict__ cursor,
    int* __restrict__ bucket) {
  int wid = threadIdx.x >> 6, lane = threadIdx.x & 63;
  int row = blockIdx.x * 4 + wid;
  const float4 v = *reinterpret_cast<const float4*>(emb + row * DIM + lane * 4);
  float ss = v.x * v.x + v.y * v.y + v.z * v.z + v.w * v.w;
#pragma unroll
  for (int off = 32; off > 0; off >>= 1) ss += __shfl_xor(ss, off);
  float scale = 1.0f / fmaxf(sqrtf(ss), 1e-12f);
  ushort4 ob;
  ob.x = f2bf(v.x * scale); ob.y = f2bf(v.y * scale);
  ob.z = f2bf(v.z * scale); ob.w = f2bf(v.w * scale);
  *reinterpret_cast<ushort4*>(ebf + row * DIM + lane * 4) = ob;
  if (lane == 0) {
    int lab = labels[row];
    int slot = atomicAdd(cursor + lab, 1);
    if (slot < BUCKET_CAP) bucket[lab * BUCKET_CAP + slot] = row;
  }
}

// ---- 2. protos: gather-sum members, normalize, write pfrag (MFMA fragment
// order, so GEMM staging is a LINEAR 1024B/wave read) + pos for member rows.
__global__ __launch_bounds__(256) void k_protos_gather(
    const unsigned short* __restrict__ ebf, const int* __restrict__ cursor,
    const int* __restrict__ bucket, unsigned short* __restrict__ pfrag,
    float* __restrict__ pos) {
  int wid = threadIdx.x >> 6, lane = threadIdx.x & 63;
  int p = blockIdx.x * 4 + wid;
  int c = cursor[p];
  if (c > BUCKET_CAP) c = BUCKET_CAP;
  float a0 = 0.f, a1 = 0.f, a2 = 0.f, a3 = 0.f;
  for (int k = 0; k < c; ++k) {
    int row = bucket[p * BUCKET_CAP + k];
    ushort4 ev = *reinterpret_cast<const ushort4*>(ebf + row * DIM + lane * 4);
    a0 += bf2f(ev.x); a1 += bf2f(ev.y); a2 += bf2f(ev.z); a3 += bf2f(ev.w);
  }
  float ss = a0 * a0 + a1 * a1 + a2 * a2 + a3 * a3;
#pragma unroll
  for (int off = 32; off > 0; off >>= 1) ss += __shfl_xor(ss, off);
  float scale = 1.0f / fmaxf(sqrtf(ss), 1e-12f);
  ushort4 ob;
  ob.x = f2bf(a0 * scale); ob.y = f2bf(a1 * scale);
  ob.z = f2bf(a2 * scale); ob.w = f2bf(a3 * scale);
  int addr = (p >> 6) * 16384 + ((((p >> 4) & 3) * 8 + (lane >> 3)) * 512) +
             ((((lane >> 1) & 3) * 16 + (p & 15)) * 8) + ((lane & 1) * 4);
  *reinterpret_cast<ushort4*>(pfrag + addr) = ob;
  float p0 = bf2f(ob.x), p1 = bf2f(ob.y), p2 = bf2f(ob.z), p3 = bf2f(ob.w);
  for (int k = 0; k < c; ++k) {
    int row = bucket[p * BUCKET_CAP + k];
    ushort4 ev = *reinterpret_cast<const ushort4*>(ebf + row * DIM + lane * 4);
    float d = bf2f(ev.x) * p0 + bf2f(ev.y) * p1 + bf2f(ev.z) * p2 +
              bf2f(ev.w) * p3;
#pragma unroll
    for (int off = 32; off > 0; off >>= 1) d += __shfl_xor(d, off);
    if (lane == 0) pos[row] = d;
  }
}

// ---- 3. fused GEMM + diag-margin + row-max + last-block loss ----
// r7 counted-vmcnt depth-3 ring (verified; T1/T5 reverted — measured null).
// Epilogue: wave-uniform diag-branch — only 4/128 (block,tile) pairs contain
// the diagonal; all others use a pure fmax tree (max3-fusable, ~64 fewer
// VALU ops/tile). Tail: last-done block reduces the loss (threadfence +
// counter; NO in-loop registers added — r9's spill came from labv/posreg
// in the hot loop, not the tail).
__global__ __attribute__((amdgpu_flat_work_group_size(512, 512)))
__attribute__((amdgpu_waves_per_eu(2, 2))) void k_gemm_negmax(
    const unsigned short* __restrict__ E, const unsigned short* __restrict__ PF,
    float* __restrict__ negp, const float* __restrict__ pos,
    int* __restrict__ counter, float* __restrict__ out) {
  extern __shared__ unsigned short smb[];  // 4 x 16384 shorts = 128 KB
  const int tid = threadIdx.x;
  const int lane = tid & 63, wid = tid >> 6;
  const int l16 = lane & 15, lk = lane >> 4;
  const int wr = (wid >> 1) * 64;  // row group (0..3)*64
  const int wch = wid & 1;         // 32-col half of each 64-col tile
  const int rowBase = blockIdx.x * 256;
  const int colBase0 = blockIdx.y * 1024;
  const int tile0 = blockIdx.y * NT;

  auto stageB = [&](int buf, int tile) {
#pragma unroll
    for (int it = 0; it < 4; ++it) {
      int c = it * 8 + wid;  // 32 chunks over 8 waves
      gload_lds16(PF + tile * 16384 + c * 512 + lane * 8,
                  &smb[buf * 16384 + c * 512 + lane * 8]);
    }
  };

  // prologue: stage tiles 0..2, load A fragments, drain once, barrier
  stageB(0, tile0);
  stageB(1, tile0 + 1);
  stageB(2, tile0 + 2);

  short8 areg[4][8];
#pragma unroll
  for (int m = 0; m < 4; ++m)
#pragma unroll
    for (int ks = 0; ks < 8; ++ks)
      areg[m][ks] = *reinterpret_cast<const short8*>(
          E + (rowBase + wr + m * 16 + l16) * DIM + ks * 32 + lk * 8);

  float rmax[4][4];
#pragma unroll
  for (int m = 0; m < 4; ++m)
#pragma unroll
    for (int r = 0; r < 4; ++r) rmax[m][r] = -3.0e38f;

  WAITV(0);
  __builtin_amdgcn_s_barrier();

  auto body = [&](int ct) {
    const unsigned short* bs = &smb[(ct & 3) * 16384];
    f32x4 acc[4][2] = {};
#pragma unroll
    for (int ks = 0; ks < 8; ++ks) {
      short8 b[2];
#pragma unroll
      for (int n = 0; n < 2; ++n)
        b[n] = *reinterpret_cast<const short8*>(
            bs + ((wch * 2 + n) * 8 + ks) * 512 + lane * 8);
#pragma unroll
      for (int m = 0; m < 4; ++m)
#pragma unroll
        for (int n = 0; n < 2; ++n)
          acc[m][n] = __builtin_amdgcn_mfma_f32_16x16x32_bf16(
              areg[m][ks], b[n], acc[m][n], 0, 0, 0);
    }
    // epilogue: diagonal intersects this tile's cols only when the tile col
    // range overlaps this block's row range -> wave-uniform branch.
    const int colLo = colBase0 + ct * 64;
    const bool hasDiag = (colLo + 64 > rowBase) && (colLo < rowBase + 256);
    if (hasDiag) {
      const int colT = colLo + wch * 32;
#pragma unroll
      for (int m = 0; m < 4; ++m) {
        int growb = rowBase + wr + m * 16 + lk * 4;
#pragma unroll
        for (int n = 0; n < 2; ++n) {
          int gcol = colT + n * 16 + l16;
#pragma unroll
          for (int r = 0; r < 4; ++r) {
            float v = acc[m][n][r];
            if (growb + r == gcol) v -= MARGIN_F;
            rmax[m][r] = fmaxf(rmax[m][r], v);
          }
        }
      }
    } else {
#pragma unroll
      for (int m = 0; m < 4; ++m)
#pragma unroll
        for (int r = 0; r < 4; ++r)
          rmax[m][r] =
              fmaxf(rmax[m][r], fmaxf(acc[m][0][r], acc[m][1][r]));
    }
  };

  for (int ct = 0; ct < NT - 3; ++ct) {  // ct = 0..12
    body(ct);
    stageB((ct + 3) & 3, tile0 + ct + 3);
    WAITV(8);  // tile ct+1 resident; ct+2, ct+3 may stay in flight
    __builtin_amdgcn_s_barrier();
  }
  body(13);
  WAITV(4);
  __builtin_amdgcn_s_barrier();
  body(14);
  WAITV(0);
  __builtin_amdgcn_s_barrier();
  body(15);

  const int slice = blockIdx.y * 2 + wch;
#pragma unroll
  for (int m = 0; m < 4; ++m) {
#pragma unroll
    for (int r = 0; r < 4; ++r) {
      float v = rmax[m][r];
      v = fmaxf(v, __shfl_xor(v, 1));
      v = fmaxf(v, __shfl_xor(v, 2));
      v = fmaxf(v, __shfl_xor(v, 4));
      v = fmaxf(v, __shfl_xor(v, 8));
      if (l16 == 0) {
        int grow = rowBase + wr + m * 16 + lk * 4 + r;
        negp[slice * B_ROWS + grow] = v;
      }
    }
  }

  // ---- last-block loss reduction (tail-only registers; no loop pressure) --
  __threadfence();
  __syncthreads();
  __shared__ int lastFlag;
  if (tid == 0) {
    int done = atomicAdd(counter, 1);
    lastFlag = (done == (int)(gridDim.x * gridDim.y) - 1);
  }
  __syncthreads();
  if (lastFlag) {
    __threadfence();  // acquire
    float s = 0.f;
    for (int i = tid; i < B_ROWS; i += 512) {
      float n = negp[i];
#pragma unroll
      for (int sl = 1; sl < NSLICE; ++sl) n = fmaxf(n, negp[sl * B_ROWS + i]);
      s += fmaxf(n - pos[i] + MARGIN_F, 0.f);
    }
#pragma unroll
    for (int off = 32; off > 0; off >>= 1) s += __shfl_xor(s, off);
    __shared__ float red[8];
    if (lane == 0) red[wid] = s;
    __syncthreads();
    if (tid == 0) {
      float t = 0.f;
#pragma unroll
      for (int w = 0; w < 8; ++w) t += red[w];
      out[0] = t * (1.0f / B_ROWS);
    }
  }
}

extern "C" void kernel_launch(void* const* d_in, const int* in_sizes, int n_in,
                              void* d_out, int out_size, void* d_ws, size_t ws_size,
                              hipStream_t stream) {
  const float* emb = (const float*)d_in[0];
  const int* labels = (const int*)d_in[1];

  char* ws = (char*)d_ws;
  int* cursor = (int*)ws;                                        // 32 KB
  int* counter = (int*)(ws + 32 * 1024);                         // 4 B
  int* bucket = (int*)(ws + 64 * 1024);                          // 1 MB
  unsigned short* ebf =
      (unsigned short*)(ws + 64 * 1024 + 1024 * 1024);           // 4 MB
  unsigned short* pfrag =
      (unsigned short*)(ws + 64 * 1024 + 5 * 1024 * 1024);       // 4 MB
  float* pos = (float*)(ws + 64 * 1024 + 9 * 1024 * 1024);       // 32 KB
  float* negp = (float*)(ws + 128 * 1024 + 9 * 1024 * 1024);     // 512 KB

  hipMemsetAsync(cursor, 0, 32 * 1024 + 64, stream);  // cursor + counter
  k_norm_index<<<B_ROWS / 4, 256, 0, stream>>>(emb, labels, ebf, cursor, bucket);
  k_protos_gather<<<B_ROWS / 4, 256, 0, stream>>>(ebf, cursor, bucket, pfrag, pos);
  hipFuncSetAttribute((const void*)k_gemm_negmax,
                      hipFuncAttributeMaxDynamicSharedMemorySize, 131072);
  k_gemm_negmax<<<dim3(32, CS), 512, 131072, stream>>>(
      ebf, pfrag, negp, pos, counter, (float*)d_out);
}

// Round 12
// 105.125 us; speedup vs baseline: 1.7752x; 1.7752x over previous
//
#include <hip/hip_runtime.h>
#include <hip/hip_bf16.h>

typedef __attribute__((ext_vector_type(8))) short short8;
typedef __attribute__((ext_vector_type(4))) float f32x4;

#define B_ROWS 8192
#define DIM 256
#define CS 8                  // column slices -> grid.y (1024 cols each)
#define NT 16                 // 64-col tiles per slice
#define NSLICE (CS * 2)       // negp slices (col-slice x wch-half)
#define MARGIN_F 0.2f
#define BUCKET_CAP 32

// counted vmcnt wait (T4): literal immediate, memory clobber pins ordering
#define WAITV(n) asm volatile("s_waitcnt vmcnt(" #n ")" ::: "memory")

__device__ __forceinline__ unsigned short f2bf(float x) {
  unsigned int u = __float_as_uint(x);
  unsigned int r = (u + 0x7fffu + ((u >> 16) & 1u)) >> 16;
  return (unsigned short)r;
}
__device__ __forceinline__ float bf2f(unsigned short h) {
  return __uint_as_float(((unsigned int)h) << 16);
}

__device__ __forceinline__ void gload_lds16(const void* g, void* l) {
  __builtin_amdgcn_global_load_lds(
      (const __attribute__((address_space(1))) unsigned int*)g,
      (__attribute__((address_space(3))) unsigned int*)l, 16, 0, 0);
}

// ---- 1. normalize rows -> bf16 e; bucket index; zero d_out ----
__global__ __launch_bounds__(256) void k_norm_index(
    const float* __restrict__ emb, const int* __restrict__ labels,
    unsigned short* __restrict__ ebf, int* __restrict__ cursor,
    int* __restrict__ bucket, float* __restrict__ out) {
  if (blockIdx.x == 0 && threadIdx.x == 0) out[0] = 0.f;
  int wid = threadIdx.x >> 6, lane = threadIdx.x & 63;
  int row = blockIdx.x * 4 + wid;
  const float4 v = *reinterpret_cast<const float4*>(emb + row * DIM + lane * 4);
  float ss = v.x * v.x + v.y * v.y + v.z * v.z + v.w * v.w;
#pragma unroll
  for (int off = 32; off > 0; off >>= 1) ss += __shfl_xor(ss, off);
  float scale = 1.0f / fmaxf(sqrtf(ss), 1e-12f);
  ushort4 ob;
  ob.x = f2bf(v.x * scale); ob.y = f2bf(v.y * scale);
  ob.z = f2bf(v.z * scale); ob.w = f2bf(v.w * scale);
  *reinterpret_cast<ushort4*>(ebf + row * DIM + lane * 4) = ob;
  if (lane == 0) {
    int lab = labels[row];
    int slot = atomicAdd(cursor + lab, 1);
    if (slot < BUCKET_CAP) bucket[lab * BUCKET_CAP + slot] = row;
  }
}

// ---- 2. protos: gather-sum members, normalize, write pfrag (MFMA fragment
// order, so GEMM staging is a LINEAR 1024B/wave read) + pos for member rows.
__global__ __launch_bounds__(256) void k_protos_gather(
    const unsigned short* __restrict__ ebf, const int* __restrict__ cursor,
    const int* __restrict__ bucket, unsigned short* __restrict__ pfrag,
    float* __restrict__ pos) {
  int wid = threadIdx.x >> 6, lane = threadIdx.x & 63;
  int p = blockIdx.x * 4 + wid;
  int c = cursor[p];
  if (c > BUCKET_CAP) c = BUCKET_CAP;
  float a0 = 0.f, a1 = 0.f, a2 = 0.f, a3 = 0.f;
  for (int k = 0; k < c; ++k) {
    int row = bucket[p * BUCKET_CAP + k];
    ushort4 ev = *reinterpret_cast<const ushort4*>(ebf + row * DIM + lane * 4);
    a0 += bf2f(ev.x); a1 += bf2f(ev.y); a2 += bf2f(ev.z); a3 += bf2f(ev.w);
  }
  float ss = a0 * a0 + a1 * a1 + a2 * a2 + a3 * a3;
#pragma unroll
  for (int off = 32; off > 0; off >>= 1) ss += __shfl_xor(ss, off);
  float scale = 1.0f / fmaxf(sqrtf(ss), 1e-12f);
  ushort4 ob;
  ob.x = f2bf(a0 * scale); ob.y = f2bf(a1 * scale);
  ob.z = f2bf(a2 * scale); ob.w = f2bf(a3 * scale);
  int addr = (p >> 6) * 16384 + ((((p >> 4) & 3) * 8 + (lane >> 3)) * 512) +
             ((((lane >> 1) & 3) * 16 + (p & 15)) * 8) + ((lane & 1) * 4);
  *reinterpret_cast<ushort4*>(pfrag + addr) = ob;
  float p0 = bf2f(ob.x), p1 = bf2f(ob.y), p2 = bf2f(ob.z), p3 = bf2f(ob.w);
  for (int k = 0; k < c; ++k) {
    int row = bucket[p * BUCKET_CAP + k];
    ushort4 ev = *reinterpret_cast<const ushort4*>(ebf + row * DIM + lane * 4);
    float d = bf2f(ev.x) * p0 + bf2f(ev.y) * p1 + bf2f(ev.z) * p2 +
              bf2f(ev.w) * p3;
#pragma unroll
    for (int off = 32; off > 0; off >>= 1) d += __shfl_xor(d, off);
    if (lane == 0) pos[row] = d;
  }
}

// ---- 3. fused GEMM + diag-margin + row-max, counted-vmcnt depth-3 ring ----
// r7-verified structure (105.9 µs total). NO threadfence / fused tail:
// device-scope fences cost ~80 µs on multi-XCD gfx950 (r9/r11 measured).
// Diag-branch epilogue kept (r11: -3.4 µs absolute VALU, verified correct).
__global__ __attribute__((amdgpu_flat_work_group_size(512, 512)))
__attribute__((amdgpu_waves_per_eu(2, 2))) void k_gemm_negmax(
    const unsigned short* __restrict__ E, const unsigned short* __restrict__ PF,
    float* __restrict__ negp) {
  extern __shared__ unsigned short smb[];  // 4 x 16384 shorts = 128 KB
  const int tid = threadIdx.x;
  const int lane = tid & 63, wid = tid >> 6;
  const int l16 = lane & 15, lk = lane >> 4;
  const int wr = (wid >> 1) * 64;  // row group (0..3)*64
  const int wch = wid & 1;         // 32-col half of each 64-col tile
  const int rowBase = blockIdx.x * 256;
  const int colBase0 = blockIdx.y * 1024;
  const int tile0 = blockIdx.y * NT;

  auto stageB = [&](int buf, int tile) {
#pragma unroll
    for (int it = 0; it < 4; ++it) {
      int c = it * 8 + wid;  // 32 chunks over 8 waves
      gload_lds16(PF + tile * 16384 + c * 512 + lane * 8,
                  &smb[buf * 16384 + c * 512 + lane * 8]);
    }
  };

  // prologue: stage tiles 0..2, load A fragments, drain once, barrier
  stageB(0, tile0);
  stageB(1, tile0 + 1);
  stageB(2, tile0 + 2);

  short8 areg[4][8];
#pragma unroll
  for (int m = 0; m < 4; ++m)
#pragma unroll
    for (int ks = 0; ks < 8; ++ks)
      areg[m][ks] = *reinterpret_cast<const short8*>(
          E + (rowBase + wr + m * 16 + l16) * DIM + ks * 32 + lk * 8);

  float rmax[4][4];
#pragma unroll
  for (int m = 0; m < 4; ++m)
#pragma unroll
    for (int r = 0; r < 4; ++r) rmax[m][r] = -3.0e38f;

  WAITV(0);
  __builtin_amdgcn_s_barrier();

  auto body = [&](int ct) {
    const unsigned short* bs = &smb[(ct & 3) * 16384];
    f32x4 acc[4][2] = {};
#pragma unroll
    for (int ks = 0; ks < 8; ++ks) {
      short8 b[2];
#pragma unroll
      for (int n = 0; n < 2; ++n)
        b[n] = *reinterpret_cast<const short8*>(
            bs + ((wch * 2 + n) * 8 + ks) * 512 + lane * 8);
#pragma unroll
      for (int m = 0; m < 4; ++m)
#pragma unroll
        for (int n = 0; n < 2; ++n)
          acc[m][n] = __builtin_amdgcn_mfma_f32_16x16x32_bf16(
              areg[m][ks], b[n], acc[m][n], 0, 0, 0);
    }
    // diag intersects this tile only when tile cols overlap block rows:
    // wave-uniform branch; non-diag path is a pure fmax tree.
    const int colLo = colBase0 + ct * 64;
    const bool hasDiag = (colLo + 64 > rowBase) && (colLo < rowBase + 256);
    if (hasDiag) {
      const int colT = colLo + wch * 32;
#pragma unroll
      for (int m = 0; m < 4; ++m) {
        int growb = rowBase + wr + m * 16 + lk * 4;
#pragma unroll
        for (int n = 0; n < 2; ++n) {
          int gcol = colT + n * 16 + l16;
#pragma unroll
          for (int r = 0; r < 4; ++r) {
            float v = acc[m][n][r];
            if (growb + r == gcol) v -= MARGIN_F;
            rmax[m][r] = fmaxf(rmax[m][r], v);
          }
        }
      }
    } else {
#pragma unroll
      for (int m = 0; m < 4; ++m)
#pragma unroll
        for (int r = 0; r < 4; ++r)
          rmax[m][r] =
              fmaxf(rmax[m][r], fmaxf(acc[m][0][r], acc[m][1][r]));
    }
  };

  for (int ct = 0; ct < NT - 3; ++ct) {  // ct = 0..12
    body(ct);
    stageB((ct + 3) & 3, tile0 + ct + 3);
    WAITV(8);  // tile ct+1 resident; ct+2, ct+3 may stay in flight
    __builtin_amdgcn_s_barrier();
  }
  body(13);
  WAITV(4);
  __builtin_amdgcn_s_barrier();
  body(14);
  WAITV(0);
  __builtin_amdgcn_s_barrier();
  body(15);

  const int slice = blockIdx.y * 2 + wch;
#pragma unroll
  for (int m = 0; m < 4; ++m) {
#pragma unroll
    for (int r = 0; r < 4; ++r) {
      float v = rmax[m][r];
      v = fmaxf(v, __shfl_xor(v, 1));
      v = fmaxf(v, __shfl_xor(v, 2));
      v = fmaxf(v, __shfl_xor(v, 4));
      v = fmaxf(v, __shfl_xor(v, 8));
      if (l16 == 0) {
        int grow = rowBase + wr + m * 16 + lk * 4 + r;
        negp[slice * B_ROWS + grow] = v;
      }
    }
  }
}

// ---- 4. loss: 32 blocks, neg = max over slices, atomicAdd partial means ----
__global__ __launch_bounds__(256) void k_loss_part(
    const float* __restrict__ negp, const float* __restrict__ pos,
    float* __restrict__ out) {
  int i = blockIdx.x * 256 + threadIdx.x;
  float n = negp[i];
#pragma unroll
  for (int s = 1; s < NSLICE; ++s) n = fmaxf(n, negp[s * B_ROWS + i]);
  float t = fmaxf(n - pos[i] + MARGIN_F, 0.f);
#pragma unroll
  for (int off = 32; off > 0; off >>= 1) t += __shfl_xor(t, off);
  __shared__ float red[4];
  if ((threadIdx.x & 63) == 0) red[threadIdx.x >> 6] = t;
  __syncthreads();
  if (threadIdx.x == 0)
    atomicAdd(out, (red[0] + red[1] + red[2] + red[3]) * (1.0f / B_ROWS));
}

extern "C" void kernel_launch(void* const* d_in, const int* in_sizes, int n_in,
                              void* d_out, int out_size, void* d_ws, size_t ws_size,
                              hipStream_t stream) {
  const float* emb = (const float*)d_in[0];
  const int* labels = (const int*)d_in[1];

  char* ws = (char*)d_ws;
  int* cursor = (int*)ws;                                        // 32 KB
  int* bucket = (int*)(ws + 32 * 1024);                          // 1 MB
  unsigned short* ebf =
      (unsigned short*)(ws + 32 * 1024 + 1024 * 1024);           // 4 MB
  unsigned short* pfrag =
      (unsigned short*)(ws + 32 * 1024 + 5 * 1024 * 1024);       // 4 MB
  float* pos = (float*)(ws + 32 * 1024 + 9 * 1024 * 1024);       // 32 KB
  float* negp = (float*)(ws + 64 * 1024 + 9 * 1024 * 1024);      // 512 KB

  hipMemsetAsync(cursor, 0, 32 * 1024, stream);
  k_norm_index<<<B_ROWS / 4, 256, 0, stream>>>(emb, labels, ebf, cursor, bucket,
                                               (float*)d_out);
  k_protos_gather<<<B_ROWS / 4, 256, 0, stream>>>(ebf, cursor, bucket, pfrag, pos);
  hipFuncSetAttribute((const void*)k_gemm_negmax,
                      hipFuncAttributeMaxDynamicSharedMemorySize, 131072);
  k_gemm_negmax<<<dim3(32, CS), 512, 131072, stream>>>(ebf, pfrag, negp);
  k_loss_part<<<32, 256, 0, stream>>>(negp, pos, (float*)d_out);
}